// Round 4
// baseline (318.184 us; speedup 1.0000x reference)
//
#include <hip/hip_runtime.h>
#include <cmath>

// ---------------------------------------------------------------------------
// T5 MHSA: x->(QKV proj, f16 MFMA GEMM) -> flash attn w/ T5 bias -> out proj
// All matmuls on MFMA. fp16 intermediates, fp32 accum.
// ---------------------------------------------------------------------------

typedef _Float16 f16x8 __attribute__((ext_vector_type(8)));
typedef _Float16 f16x4 __attribute__((ext_vector_type(4)));
typedef float    f32x4 __attribute__((ext_vector_type(4)));

#define NEG_INF (-__builtin_inff())
#define LOG2E 1.4426950408889634f

#if __has_builtin(__builtin_amdgcn_exp2f)
#define EXP2(x) __builtin_amdgcn_exp2f(x)
#else
#define EXP2(x) exp2f(x)
#endif

__device__ __forceinline__ void gl_lds16(const void* g, void* l) {
  __builtin_amdgcn_global_load_lds(
      (__attribute__((address_space(1))) void*)g,
      (__attribute__((address_space(3))) void*)l,
      16, 0, 0);
}

__device__ __forceinline__ f32x4 mfma32(f16x8 a, f16x8 b, f32x4 c) {
  return __builtin_amdgcn_mfma_f32_16x16x32_f16(a, b, c, 0, 0, 0);
}
__device__ __forceinline__ f32x4 mfma16(f16x4 a, f16x4 b, f32x4 c) {
  return __builtin_amdgcn_mfma_f32_16x16x16f16(a, b, c, 0, 0, 0);
}

// -------------------------------- convert ---------------------------------
__global__ void cvt_kernel(const float* __restrict__ in,
                           _Float16* __restrict__ out, int n4) {
  int i = blockIdx.x * blockDim.x + threadIdx.x;
  if (i >= n4) return;
  float4 v = reinterpret_cast<const float4*>(in)[i];
  f16x4 o;
  o[0] = (_Float16)v.x; o[1] = (_Float16)v.y;
  o[2] = (_Float16)v.z; o[3] = (_Float16)v.w;
  reinterpret_cast<f16x4*>(out)[i] = o;
}

// --------------------------------- GEMM -----------------------------------
// C = A(MxK) * Bm(NxK)^T.  128x128 tile, BK=32, 4 waves (2x2 of 64x64).
template <int MODE>
__global__ __launch_bounds__(256, 2) void gemm_kernel(
    const _Float16* __restrict__ A, const _Float16* __restrict__ Bm,
    int M, int N, int K,
    const float* __restrict__ bias_q, const float* __restrict__ bias_v,
    _Float16* __restrict__ qkbuf, _Float16* __restrict__ vtbuf,
    const float* __restrict__ bias_o, float* __restrict__ outf) {
  __shared__ __align__(16) _Float16 lds_a[128 * 32];
  __shared__ __align__(16) _Float16 lds_b[128 * 32];
  const int t = threadIdx.x;
  const int w = t >> 6;
  const int lane = t & 63;
  const int lq = lane & 15, lg = lane >> 4;
  const int wr = w >> 1, wc = w & 1;
  const int m0 = blockIdx.y * 128, n0 = blockIdx.x * 128;

  const _Float16* pA0 = A + (size_t)(m0 + (t >> 2)) * K + (t & 3) * 8;
  const _Float16* pA1 = pA0 + (size_t)64 * K;
  const _Float16* pB0 = Bm + (size_t)(n0 + (t >> 2)) * K + (t & 3) * 8;
  const _Float16* pB1 = pB0 + (size_t)64 * K;
  _Float16* la0 = &lds_a[(w * 64) * 8];
  _Float16* la1 = &lds_a[(256 + w * 64) * 8];
  _Float16* lb0 = &lds_b[(w * 64) * 8];
  _Float16* lb1 = &lds_b[(256 + w * 64) * 8];

  f32x4 acc[4][4];
#pragma unroll
  for (int mi = 0; mi < 4; ++mi)
#pragma unroll
    for (int ni = 0; ni < 4; ++ni) acc[mi][ni] = (f32x4){0.f, 0.f, 0.f, 0.f};

  for (int k0 = 0; k0 < K; k0 += 32) {
    __syncthreads();
    gl_lds16(pA0 + k0, la0);
    gl_lds16(pA1 + k0, la1);
    gl_lds16(pB0 + k0, lb0);
    gl_lds16(pB1 + k0, lb1);
    __syncthreads();
    f16x8 af[4], bfr[4];
#pragma unroll
    for (int mi = 0; mi < 4; ++mi)
      af[mi] = *(const f16x8*)&lds_a[(wr * 64 + mi * 16 + lq) * 32 + lg * 8];
#pragma unroll
    for (int ni = 0; ni < 4; ++ni)
      bfr[ni] = *(const f16x8*)&lds_b[(wc * 64 + ni * 16 + lq) * 32 + lg * 8];
#pragma unroll
    for (int mi = 0; mi < 4; ++mi)
#pragma unroll
      for (int ni = 0; ni < 4; ++ni)
        acc[mi][ni] = mfma32(af[mi], bfr[ni], acc[mi][ni]);
  }

  if (MODE == 0) {
    const bool isqk = (n0 < 2048);
#pragma unroll
    for (int mi = 0; mi < 4; ++mi)
#pragma unroll
      for (int ni = 0; ni < 4; ++ni)
#pragma unroll
        for (int r = 0; r < 4; ++r) {
          const int mg = m0 + wr * 64 + mi * 16 + lg * 4 + r;
          const int ng = n0 + wc * 64 + ni * 16 + lq;
          const int bb = mg >> 10, ii = mg & 1023;
          float val = acc[mi][ni][r];
          if (isqk) {
            val += bias_q[ng];
            const int hh = ng >> 7, cc = ng & 127;
            qkbuf[((size_t)((bb * 16 + hh) * 1024 + ii)) * 128 + cc] =
                (_Float16)val;
          } else {
            const int nn = ng - 2048;
            val += bias_v[nn];
            const int hh = nn >> 6, dv = nn & 63;
            vtbuf[((size_t)((bb * 16 + hh) * 64 + dv)) * 1024 + ii] =
                (_Float16)val;
          }
        }
  } else {
#pragma unroll
    for (int mi = 0; mi < 4; ++mi)
#pragma unroll
      for (int ni = 0; ni < 4; ++ni)
#pragma unroll
        for (int r = 0; r < 4; ++r) {
          const int mg = m0 + wr * 64 + mi * 16 + lg * 4 + r;
          const int ng = n0 + wc * 64 + ni * 16 + lq;
          outf[(size_t)mg * N + ng] = acc[mi][ni][r] + bias_o[ng];
        }
  }
}

// ------------------------------- attention --------------------------------
// Block = 4 waves. Each wave owns TWO 16-row q-subtiles (s, 63-s) of one
// (b,h) for causal balance; K/V fragments shared by both q-sets.
// S^T = mfma_16x16x32(K,Q): lane holds S[q=lq][j=j0+lg*4+r], which IS the
// A-fragment of mfma_16x16x16 -> PV without any repack.
// Softmax: defer-max on PER-LANE max (common path has ZERO cross-lane ops);
// rare wave-uniform trigger does the row reduce via __shfl_xor + rescale.
// Invariant: after each tile, all xs <= m_run + 8 -> p <= 2^8 (f16-safe).
__device__ __forceinline__ void attn_tile(
    const f16x8& qf0, const f16x8& qf1, const f16x8 (&kf)[4],
    const f16x4 (&vf)[4][2], const float* __restrict__ tab, int qi, int j0,
    int lg4, float& m_run, float& l_part, f32x4 (&oacc)[4]) {
  f32x4 st0 = {0.f, 0.f, 0.f, 0.f}, st1 = {0.f, 0.f, 0.f, 0.f};
  st0 = mfma32(kf[0], qf0, st0);
  st0 = mfma32(kf[1], qf1, st0);
  st1 = mfma32(kf[2], qf0, st1);
  st1 = mfma32(kf[3], qf1, st1);
  float xs[8];
  float lmax = NEG_INF;
#pragma unroll
  for (int hh = 0; hh < 2; ++hh)
#pragma unroll
    for (int r = 0; r < 4; ++r) {
      const int jj = j0 + hh * 16 + lg4 + r;
      const int dd = qi - jj;
      const int idx = dd < 0 ? 0 : (dd > 128 ? 128 : dd);
      const float sv = hh ? st1[r] : st0[r];
      const float xv =
          (dd < 0) ? NEG_INF : fmaf(sv, 0.125f * LOG2E, tab[idx]);
      xs[hh * 4 + r] = xv;
      lmax = fmaxf(lmax, xv);
    }
  // defer-max: per-lane check, wave-uniform rare branch (tile 0 always fires,
  // establishing a finite per-row m_run).
  if (__any(lmax > m_run + 8.0f)) {
    float tmax = fmaxf(lmax, __shfl_xor(lmax, 16));
    tmax = fmaxf(tmax, __shfl_xor(tmax, 32));  // row max, all 4 groups agree
    const float m_new = fmaxf(m_run, tmax);
    const float sf = EXP2(m_run - m_new);  // first tile: exp2(-inf)=0
    m_run = m_new;
    l_part *= sf;
    f32x4 sfv;
#pragma unroll
    for (int r = 0; r < 4; ++r) sfv[r] = __shfl(sf, lg4 + r);
#pragma unroll
    for (int db = 0; db < 4; ++db) oacc[db] *= sfv;
  }
#pragma unroll
  for (int e = 0; e < 8; ++e) xs[e] = EXP2(xs[e] - m_run);
  l_part +=
      ((xs[0] + xs[1]) + (xs[2] + xs[3])) + ((xs[4] + xs[5]) + (xs[6] + xs[7]));
  f16x4 ph0, ph1;
#pragma unroll
  for (int r = 0; r < 4; ++r) {
    ph0[r] = (_Float16)xs[r];
    ph1[r] = (_Float16)xs[4 + r];
  }
#pragma unroll
  for (int db = 0; db < 4; ++db) {
    oacc[db] = mfma16(ph0, vf[db][0], oacc[db]);
    oacc[db] = mfma16(ph1, vf[db][1], oacc[db]);
  }
}

__global__ __launch_bounds__(256, 4) void attn_kernel(
    const _Float16* __restrict__ qk,  // [B*H][1024][128] (q | k)
    const _Float16* __restrict__ vt,  // [B*H][64][1024]  (V^T)
    const float* __restrict__ bias,   // [32][16]
    _Float16* __restrict__ ao) {      // [B][1024][H*64]
  __shared__ float tab[132];
  const int t = threadIdx.x;
  const int bid = blockIdx.x;
  // XCD swizzle: the 8 blocks of one (b,h) share bid%8 -> same XCD's L2
  const int bh = (bid & 7) * 16 + (bid >> 6);
  const int b4 = (bid >> 3) & 7;
  const int h = bh & 15, b = bh >> 4;
  if (t < 129) {
    const int bucket =
        (t <= 16) ? t : 16 + (int)(log((double)(t - 15)) * 15.0 / log(113.0));
    tab[t] = bias[bucket * 16 + h] * LOG2E;
  }
  __syncthreads();

  const int w = t >> 6, lane = t & 63;
  const int lq = lane & 15, lg = lane >> 4;
  const int lg4 = lg * 4;
  const int sA = b4 * 4 + w;  // [0,32)
  const int sB = 63 - sA;     // [32,64)
  const int q0A = sA * 16, q0B = sB * 16;
  const int qA = q0A + lq, qB = q0B + lq;
  const _Float16* qkb = qk + (size_t)bh * 1024 * 128;
  const _Float16* kb = qkb + 64;
  const _Float16* vtb = vt + (size_t)bh * 64 * 1024;

  const f16x8 qfA0 = *(const f16x8*)&qkb[qA * 128 + lg * 8];
  const f16x8 qfA1 = *(const f16x8*)&qkb[qA * 128 + 32 + lg * 8];
  const f16x8 qfB0 = *(const f16x8*)&qkb[qB * 128 + lg * 8];
  const f16x8 qfB1 = *(const f16x8*)&qkb[qB * 128 + 32 + lg * 8];

  f32x4 oA[4], oB[4];
#pragma unroll
  for (int db = 0; db < 4; ++db) {
    oA[db] = (f32x4){0.f, 0.f, 0.f, 0.f};
    oB[db] = (f32x4){0.f, 0.f, 0.f, 0.f};
  }
  float mA = NEG_INF, lAp = 0.f, mB = NEG_INF, lBp = 0.f;
  const int njtA = (q0A + 47) >> 5;
  const int njtB = (q0B + 47) >> 5;

  f16x8 kcur[4], knxt[4];
#pragma unroll
  for (int i = 0; i < 2; ++i) {
    kcur[i * 2 + 0] =
        *(const f16x8*)&kb[(size_t)(i * 16 + lq) * 128 + lg * 8];
    kcur[i * 2 + 1] =
        *(const f16x8*)&kb[(size_t)(i * 16 + lq) * 128 + 32 + lg * 8];
  }

  for (int jt = 0; jt < njtB; ++jt) {
    const int j0 = jt * 32;
    const int jn = (jt + 1 < njtB) ? j0 + 32 : 0;  // safe dummy on last iter
    // prefetch next K tile (register double-buffer)
#pragma unroll
    for (int i = 0; i < 2; ++i) {
      knxt[i * 2 + 0] =
          *(const f16x8*)&kb[(size_t)(jn + i * 16 + lq) * 128 + lg * 8];
      knxt[i * 2 + 1] =
          *(const f16x8*)&kb[(size_t)(jn + i * 16 + lq) * 128 + 32 + lg * 8];
    }
    // V for this tile: issued here, consumed at end of chain by PV
    f16x4 vf[4][2];
#pragma unroll
    for (int db = 0; db < 4; ++db) {
      vf[db][0] = *(const f16x4*)&vtb[(size_t)(db * 16 + lq) * 1024 + j0 + lg4];
      vf[db][1] =
          *(const f16x4*)&vtb[(size_t)(db * 16 + lq) * 1024 + j0 + 16 + lg4];
    }
    if (jt < njtA)
      attn_tile(qfA0, qfA1, kcur, vf, tab, qA, j0, lg4, mA, lAp, oA);
    attn_tile(qfB0, qfB1, kcur, vf, tab, qB, j0, lg4, mB, lBp, oB);
#pragma unroll
    for (int i = 0; i < 4; ++i) kcur[i] = knxt[i];
  }

  _Float16* aob = ao + ((size_t)b * 1024) * 1024 + h * 64;
  {
    float lt = lAp + __shfl_xor(lAp, 16);
    lt += __shfl_xor(lt, 32);
    f32x4 linv;
#pragma unroll
    for (int r = 0; r < 4; ++r) linv[r] = 1.0f / __shfl(lt, lg4 + r);
#pragma unroll
    for (int db = 0; db < 4; ++db)
#pragma unroll
      for (int r = 0; r < 4; ++r)
        aob[(size_t)(q0A + lg4 + r) * 1024 + db * 16 + lq] =
            (_Float16)(oA[db][r] * linv[r]);
  }
  {
    float lt = lBp + __shfl_xor(lBp, 16);
    lt += __shfl_xor(lt, 32);
    f32x4 linv;
#pragma unroll
    for (int r = 0; r < 4; ++r) linv[r] = 1.0f / __shfl(lt, lg4 + r);
#pragma unroll
    for (int db = 0; db < 4; ++db)
#pragma unroll
      for (int r = 0; r < 4; ++r)
        aob[(size_t)(q0B + lg4 + r) * 1024 + db * 16 + lq] =
            (_Float16)(oB[db][r] * linv[r]);
  }
}

// -------------------------------- launch ----------------------------------
extern "C" void kernel_launch(void* const* d_in, const int* in_sizes, int n_in,
                              void* d_out, int out_size, void* d_ws,
                              size_t ws_size, hipStream_t stream) {
  const float* x = (const float*)d_in[0];
  const float* qk_w = (const float*)d_in[1];
  const float* qk_b = (const float*)d_in[2];
  const float* v_w = (const float*)d_in[3];
  const float* v_b = (const float*)d_in[4];
  const float* out_w = (const float*)d_in[5];
  const float* out_b = (const float*)d_in[6];
  const float* bias = (const float*)d_in[7];
  float* out = (float*)d_out;

  // workspace (fp16 elems): xb 8M | wb 3M | owb 1M | qk 16M | vt 8M | ao 8M
  _Float16* xb = (_Float16*)d_ws;
  _Float16* wb = xb + (size_t)8388608;
  _Float16* owb = wb + (size_t)3145728;
  _Float16* qkbuf = owb + (size_t)1048576;
  _Float16* vtbuf = qkbuf + (size_t)16777216;
  _Float16* ao = vtbuf + (size_t)8388608;

  cvt_kernel<<<8192, 256, 0, stream>>>(x, xb, 2097152);
  cvt_kernel<<<2048, 256, 0, stream>>>(qk_w, wb, 524288);
  cvt_kernel<<<1024, 256, 0, stream>>>(v_w, wb + 2097152, 262144);
  cvt_kernel<<<1024, 256, 0, stream>>>(out_w, owb, 262144);

  // fused QKV projection: M=8192, N=3072 (2048 qk | 1024 v), K=1024
  gemm_kernel<0><<<dim3(24, 64), 256, 0, stream>>>(
      xb, wb, 8192, 3072, 1024, qk_b, v_b, qkbuf, vtbuf, nullptr, nullptr);

  // flash attention: B*H*8 balanced blocks
  attn_kernel<<<1024, 256, 0, stream>>>(qkbuf, vtbuf, bias, ao);

  // output projection: M=8192, N=1024, K=1024 -> fp32 d_out
  gemm_kernel<1><<<dim3(8, 64), 256, 0, stream>>>(
      ao, owb, 8192, 1024, 1024, nullptr, nullptr, nullptr, nullptr, out_b, out);
}

// Round 5
// 193.521 us; speedup vs baseline: 1.6442x; 1.6442x over previous
//
#include <hip/hip_runtime.h>
#include <cmath>

// ---------------------------------------------------------------------------
// T5 MHSA: x->(QKV proj, f16 MFMA GEMM) -> flash attn w/ T5 bias -> out proj
// All matmuls on MFMA. fp16 intermediates, fp32 accum.
// ---------------------------------------------------------------------------

typedef _Float16 f16x8 __attribute__((ext_vector_type(8)));
typedef _Float16 f16x4 __attribute__((ext_vector_type(4)));
typedef float    f32x4 __attribute__((ext_vector_type(4)));

#define NEG_INF (-__builtin_inff())
#define LOG2E 1.4426950408889634f

#if __has_builtin(__builtin_amdgcn_exp2f)
#define EXP2(x) __builtin_amdgcn_exp2f(x)
#else
#define EXP2(x) exp2f(x)
#endif

__device__ __forceinline__ void gl_lds16(const void* g, void* l) {
  __builtin_amdgcn_global_load_lds(
      (__attribute__((address_space(1))) void*)g,
      (__attribute__((address_space(3))) void*)l,
      16, 0, 0);
}

__device__ __forceinline__ f32x4 mfma32(f16x8 a, f16x8 b, f32x4 c) {
  return __builtin_amdgcn_mfma_f32_16x16x32_f16(a, b, c, 0, 0, 0);
}
__device__ __forceinline__ f32x4 mfma16(f16x4 a, f16x4 b, f32x4 c) {
  return __builtin_amdgcn_mfma_f32_16x16x16f16(a, b, c, 0, 0, 0);
}

// -------------------------------- convert ---------------------------------
__global__ void cvt_kernel(const float* __restrict__ in,
                           _Float16* __restrict__ out, int n4) {
  int i = blockIdx.x * blockDim.x + threadIdx.x;
  if (i >= n4) return;
  float4 v = reinterpret_cast<const float4*>(in)[i];
  f16x4 o;
  o[0] = (_Float16)v.x; o[1] = (_Float16)v.y;
  o[2] = (_Float16)v.z; o[3] = (_Float16)v.w;
  reinterpret_cast<f16x4*>(out)[i] = o;
}

// --------------------------------- GEMM -----------------------------------
// C = A(MxK) * Bm(NxK)^T.  128x128 tile, BK=32, 4 waves (2x2 of 64x64).
template <int MODE>
__global__ __launch_bounds__(256, 2) void gemm_kernel(
    const _Float16* __restrict__ A, const _Float16* __restrict__ Bm,
    int M, int N, int K,
    const float* __restrict__ bias_q, const float* __restrict__ bias_v,
    _Float16* __restrict__ qkbuf, _Float16* __restrict__ vtbuf,
    const float* __restrict__ bias_o, float* __restrict__ outf) {
  __shared__ __align__(16) _Float16 lds_a[128 * 32];
  __shared__ __align__(16) _Float16 lds_b[128 * 32];
  const int t = threadIdx.x;
  const int w = t >> 6;
  const int lane = t & 63;
  const int lq = lane & 15, lg = lane >> 4;
  const int wr = w >> 1, wc = w & 1;
  const int m0 = blockIdx.y * 128, n0 = blockIdx.x * 128;

  const _Float16* pA0 = A + (size_t)(m0 + (t >> 2)) * K + (t & 3) * 8;
  const _Float16* pA1 = pA0 + (size_t)64 * K;
  const _Float16* pB0 = Bm + (size_t)(n0 + (t >> 2)) * K + (t & 3) * 8;
  const _Float16* pB1 = pB0 + (size_t)64 * K;
  _Float16* la0 = &lds_a[(w * 64) * 8];
  _Float16* la1 = &lds_a[(256 + w * 64) * 8];
  _Float16* lb0 = &lds_b[(w * 64) * 8];
  _Float16* lb1 = &lds_b[(256 + w * 64) * 8];

  f32x4 acc[4][4];
#pragma unroll
  for (int mi = 0; mi < 4; ++mi)
#pragma unroll
    for (int ni = 0; ni < 4; ++ni) acc[mi][ni] = (f32x4){0.f, 0.f, 0.f, 0.f};

  for (int k0 = 0; k0 < K; k0 += 32) {
    __syncthreads();
    gl_lds16(pA0 + k0, la0);
    gl_lds16(pA1 + k0, la1);
    gl_lds16(pB0 + k0, lb0);
    gl_lds16(pB1 + k0, lb1);
    __syncthreads();
    f16x8 af[4], bfr[4];
#pragma unroll
    for (int mi = 0; mi < 4; ++mi)
      af[mi] = *(const f16x8*)&lds_a[(wr * 64 + mi * 16 + lq) * 32 + lg * 8];
#pragma unroll
    for (int ni = 0; ni < 4; ++ni)
      bfr[ni] = *(const f16x8*)&lds_b[(wc * 64 + ni * 16 + lq) * 32 + lg * 8];
#pragma unroll
    for (int mi = 0; mi < 4; ++mi)
#pragma unroll
      for (int ni = 0; ni < 4; ++ni)
        acc[mi][ni] = mfma32(af[mi], bfr[ni], acc[mi][ni]);
  }

  if (MODE == 0) {
    const bool isqk = (n0 < 2048);
#pragma unroll
    for (int mi = 0; mi < 4; ++mi)
#pragma unroll
      for (int ni = 0; ni < 4; ++ni)
#pragma unroll
        for (int r = 0; r < 4; ++r) {
          const int mg = m0 + wr * 64 + mi * 16 + lg * 4 + r;
          const int ng = n0 + wc * 64 + ni * 16 + lq;
          const int bb = mg >> 10, ii = mg & 1023;
          float val = acc[mi][ni][r];
          if (isqk) {
            val += bias_q[ng];
            const int hh = ng >> 7, cc = ng & 127;
            qkbuf[((size_t)((bb * 16 + hh) * 1024 + ii)) * 128 + cc] =
                (_Float16)val;
          } else {
            const int nn = ng - 2048;
            val += bias_v[nn];
            const int hh = nn >> 6, dv = nn & 63;
            vtbuf[((size_t)((bb * 16 + hh) * 64 + dv)) * 1024 + ii] =
                (_Float16)val;
          }
        }
  } else {
#pragma unroll
    for (int mi = 0; mi < 4; ++mi)
#pragma unroll
      for (int ni = 0; ni < 4; ++ni)
#pragma unroll
        for (int r = 0; r < 4; ++r) {
          const int mg = m0 + wr * 64 + mi * 16 + lg * 4 + r;
          const int ng = n0 + wc * 64 + ni * 16 + lq;
          outf[(size_t)mg * N + ng] = acc[mi][ni][r] + bias_o[ng];
        }
  }
}

// ------------------------------- attention --------------------------------
// Block = 4 waves, owns q-tile PAIR (tA=b4, tB=15-b4) of one (b,h): constant
// work per block (17 tile-units), all waves share the same j-range ->
// barrier-synced LDS staging of K/V tiles (KVBLK=64), double-buffered,
// coalesced global_load_lds with pre-swizzled source (XOR chunk swizzle) so
// swizzled LDS reads are bank-conflict-free.
// S^T = mfma_16x16x32(K,Q): lane holds S[q=lq][j=js*16+lg*4+r], which IS the
// A-fragment of mfma_16x16x16 -> PV without repack.
// Softmax: defer-max on per-lane max (common path: zero cross-lane ops).
__device__ __forceinline__ void stage_kv(const _Float16* __restrict__ kb,
                                         const _Float16* __restrict__ vtb,
                                         int j0, _Float16* kl, _Float16* vl,
                                         int t) {
  const int r0 = t >> 3, c0 = t & 7;
  const int r1 = r0 + 32;
  const int kc0 = c0 ^ (r0 & 7), kc1 = c0 ^ (r1 & 7);
  // K tile rows j (64 x 64 f16); source row stride 128 (q|k interleaved)
  gl_lds16(kb + (size_t)(j0 + r0) * 128 + kc0 * 8, kl + t * 8);
  gl_lds16(kb + (size_t)(j0 + r1) * 128 + kc1 * 8, kl + (t + 256) * 8);
  // V^T tile rows d (64 x 64 f16); source row stride 1024
  gl_lds16(vtb + (size_t)r0 * 1024 + j0 + kc0 * 8, vl + t * 8);
  gl_lds16(vtb + (size_t)r1 * 1024 + j0 + kc1 * 8, vl + (t + 256) * 8);
}

__device__ __forceinline__ void softmax16(f32x4 (&st)[4], f16x4 (&ph)[4],
                                          int qi, int j0, bool far,
                                          const float* __restrict__ tab,
                                          float t128, int lg4, float& m_run,
                                          float& l_part, f32x4 (&oacc)[4]) {
  float xs[16];
  float lmax = NEG_INF;
  if (far) {  // all dd > 128: bias = tab[128], no mask possible
#pragma unroll
    for (int js = 0; js < 4; ++js)
#pragma unroll
      for (int r = 0; r < 4; ++r) {
        const float xv = fmaf(st[js][r], 0.125f * LOG2E, t128);
        xs[js * 4 + r] = xv;
        lmax = fmaxf(lmax, xv);
      }
  } else {
#pragma unroll
    for (int js = 0; js < 4; ++js)
#pragma unroll
      for (int r = 0; r < 4; ++r) {
        const int jj = j0 + js * 16 + lg4 + r;
        const int dd = qi - jj;
        const int idx = dd < 0 ? 0 : (dd > 128 ? 128 : dd);
        const float xv =
            (dd < 0) ? NEG_INF : fmaf(st[js][r], 0.125f * LOG2E, tab[idx]);
        xs[js * 4 + r] = xv;
        lmax = fmaxf(lmax, xv);
      }
  }
  // defer-max: invariant xs <= m_run + 8 after this block -> p <= 2^8
  if (__any(lmax > m_run + 8.0f)) {
    float tmax = fmaxf(lmax, __shfl_xor(lmax, 16));
    tmax = fmaxf(tmax, __shfl_xor(tmax, 32));
    const float m_new = fmaxf(m_run, tmax);
    const float sf = EXP2(m_run - m_new);
    m_run = m_new;
    l_part *= sf;
    f32x4 sfv;
#pragma unroll
    for (int r = 0; r < 4; ++r) sfv[r] = __shfl(sf, lg4 + r);
#pragma unroll
    for (int db = 0; db < 4; ++db) oacc[db] *= sfv;
  }
  float ls = 0.f;
#pragma unroll
  for (int js = 0; js < 4; ++js)
#pragma unroll
    for (int r = 0; r < 4; ++r) {
      const float p = EXP2(xs[js * 4 + r] - m_run);
      ls += p;
      ph[js][r] = (_Float16)p;
    }
  l_part += ls;
}

__global__ __launch_bounds__(256, 4) void attn_kernel(
    const _Float16* __restrict__ qk,  // [B*H][1024][128] (q | k)
    const _Float16* __restrict__ vt,  // [B*H][64][1024]  (V^T)
    const float* __restrict__ bias,   // [32][16]
    _Float16* __restrict__ ao) {      // [B][1024][H*64]
  __shared__ __align__(16) _Float16 kls[2][64 * 64];
  __shared__ __align__(16) _Float16 vls[2][64 * 64];
  __shared__ float tab[132];
  const int t = threadIdx.x;
  const int bid = blockIdx.x;
  // XCD swizzle: XCD x serves bh [x*16, x*16+16) -> K/V working set ~4MB/L2
  const int bh = (bid & 7) * 16 + (bid >> 6);
  const int b4 = (bid >> 3) & 7;
  const int h = bh & 15, b = bh >> 4;
  if (t < 129) {
    const int bucket =
        (t <= 16) ? t : 16 + (int)(log((double)(t - 15)) * 15.0 / log(113.0));
    tab[t] = bias[bucket * 16 + h] * LOG2E;
  }

  const int w = t >> 6, lane = t & 63;
  const int lq = lane & 15, lg = lane >> 4;
  const int lg4 = lg * 4, lg8 = lg * 8;
  const int tA = b4, tB = 15 - b4;  // q-tile pair: tA+1 + tB+1 = 17 units
  const int q0A = tA * 64 + w * 16, q0B = tB * 64 + w * 16;
  const int qA = q0A + lq, qB = q0B + lq;
  const _Float16* qkb = qk + (size_t)bh * 1024 * 128;
  const _Float16* kb = qkb + 64;
  const _Float16* vtb = vt + (size_t)bh * 64 * 1024;

  const f16x8 qfA0 = *(const f16x8*)&qkb[qA * 128 + lg8];
  const f16x8 qfA1 = *(const f16x8*)&qkb[qA * 128 + 32 + lg8];
  const f16x8 qfB0 = *(const f16x8*)&qkb[qB * 128 + lg8];
  const f16x8 qfB1 = *(const f16x8*)&qkb[qB * 128 + 32 + lg8];

  f32x4 oA[4], oB[4];
#pragma unroll
  for (int db = 0; db < 4; ++db) {
    oA[db] = (f32x4){0.f, 0.f, 0.f, 0.f};
    oB[db] = (f32x4){0.f, 0.f, 0.f, 0.f};
  }
  float mA = NEG_INF, lAp = 0.f, mB = NEG_INF, lBp = 0.f;

  stage_kv(kb, vtb, 0, kls[0], vls[0], t);
  __syncthreads();
  const float t128 = tab[128];
  const int krsw = lq & 7;
  const int vsw = (lq & 7) << 1;
  int cur = 0;

  for (int jt = 0; jt <= tB; ++jt) {
    const int j0 = jt * 64;
    if (jt < tB) stage_kv(kb, vtb, j0 + 64, kls[cur ^ 1], vls[cur ^ 1], t);
    const bool aact = (jt <= tA);
    const _Float16* kbf = kls[cur];
    const _Float16* vbf = vls[cur];

    // QK^T for both q-sets from shared K frags (swizzled LDS reads)
    f32x4 stA[4], stB[4];
#pragma unroll
    for (int js = 0; js < 4; ++js) {
      const int rowb = (js * 16 + lq) * 64;
      const f16x8 kf0 = *(const f16x8*)&kbf[rowb + ((lg ^ krsw) << 3)];
      const f16x8 kf1 = *(const f16x8*)&kbf[rowb + (((lg + 4) ^ krsw) << 3)];
      if (aact) {
        stA[js] = mfma32(kf0, qfA0, (f32x4){0.f, 0.f, 0.f, 0.f});
        stA[js] = mfma32(kf1, qfA1, stA[js]);
      }
      stB[js] = mfma32(kf0, qfB0, (f32x4){0.f, 0.f, 0.f, 0.f});
      stB[js] = mfma32(kf1, qfB1, stB[js]);
    }

    f16x4 phA[4], phB[4];
    if (aact)
      softmax16(stA, phA, qA, j0, q0A - j0 >= 192, tab, t128, lg4, mA, lAp,
                oA);
    softmax16(stB, phB, qB, j0, q0B - j0 >= 192, tab, t128, lg4, mB, lBp, oB);

    // PV from shared V frags (swizzled LDS reads)
#pragma unroll
    for (int js = 0; js < 4; ++js)
#pragma unroll
      for (int db = 0; db < 4; ++db) {
        const f16x4 vf = *(const f16x4*)&vbf[(db * 16 + lq) * 64 +
                                             ((((js << 2) + lg) ^ vsw) << 2)];
        if (aact) oA[db] = mfma16(phA[js], vf, oA[db]);
        oB[db] = mfma16(phB[js], vf, oB[db]);
      }

    __syncthreads();
    cur ^= 1;
  }

  _Float16* aob = ao + ((size_t)b * 1024) * 1024 + h * 64;
  {
    float lt = lAp + __shfl_xor(lAp, 16);
    lt += __shfl_xor(lt, 32);
    f32x4 linv;
#pragma unroll
    for (int r = 0; r < 4; ++r) linv[r] = 1.0f / __shfl(lt, lg4 + r);
#pragma unroll
    for (int db = 0; db < 4; ++db)
#pragma unroll
      for (int r = 0; r < 4; ++r)
        aob[(size_t)(q0A + lg4 + r) * 1024 + db * 16 + lq] =
            (_Float16)(oA[db][r] * linv[r]);
  }
  {
    float lt = lBp + __shfl_xor(lBp, 16);
    lt += __shfl_xor(lt, 32);
    f32x4 linv;
#pragma unroll
    for (int r = 0; r < 4; ++r) linv[r] = 1.0f / __shfl(lt, lg4 + r);
#pragma unroll
    for (int db = 0; db < 4; ++db)
#pragma unroll
      for (int r = 0; r < 4; ++r)
        aob[(size_t)(q0B + lg4 + r) * 1024 + db * 16 + lq] =
            (_Float16)(oB[db][r] * linv[r]);
  }
}

// -------------------------------- launch ----------------------------------
extern "C" void kernel_launch(void* const* d_in, const int* in_sizes, int n_in,
                              void* d_out, int out_size, void* d_ws,
                              size_t ws_size, hipStream_t stream) {
  const float* x = (const float*)d_in[0];
  const float* qk_w = (const float*)d_in[1];
  const float* qk_b = (const float*)d_in[2];
  const float* v_w = (const float*)d_in[3];
  const float* v_b = (const float*)d_in[4];
  const float* out_w = (const float*)d_in[5];
  const float* out_b = (const float*)d_in[6];
  const float* bias = (const float*)d_in[7];
  float* out = (float*)d_out;

  // workspace (fp16 elems): xb 8M | wb 3M | owb 1M | qk 16M | vt 8M | ao 8M
  _Float16* xb = (_Float16*)d_ws;
  _Float16* wb = xb + (size_t)8388608;
  _Float16* owb = wb + (size_t)3145728;
  _Float16* qkbuf = owb + (size_t)1048576;
  _Float16* vtbuf = qkbuf + (size_t)16777216;
  _Float16* ao = vtbuf + (size_t)8388608;

  cvt_kernel<<<8192, 256, 0, stream>>>(x, xb, 2097152);
  cvt_kernel<<<2048, 256, 0, stream>>>(qk_w, wb, 524288);
  cvt_kernel<<<1024, 256, 0, stream>>>(v_w, wb + 2097152, 262144);
  cvt_kernel<<<1024, 256, 0, stream>>>(out_w, owb, 262144);

  // fused QKV projection: M=8192, N=3072 (2048 qk | 1024 v), K=1024
  gemm_kernel<0><<<dim3(24, 64), 256, 0, stream>>>(
      xb, wb, 8192, 3072, 1024, qk_b, v_b, qkbuf, vtbuf, nullptr, nullptr);

  // flash attention: 8 balanced blocks per (b,h)
  attn_kernel<<<1024, 256, 0, stream>>>(qkbuf, vtbuf, bias, ao);

  // output projection: M=8192, N=1024, K=1024 -> fp32 d_out
  gemm_kernel<1><<<dim3(8, 64), 256, 0, stream>>>(
      ao, owb, 8192, 1024, 1024, nullptr, nullptr, nullptr, nullptr, out_b, out);
}